// Round 2
// baseline (2032.687 us; speedup 1.0000x reference)
//
#include <hip/hip_runtime.h>
#include <hip/hip_bf16.h>
#include <math.h>

#define B_SZ 4
#define LSEQ 2048
#define DM 1024
#define DI 2048
#define DH 1024
#define DS 16
#define DTR 64
#define RTOT 96
#define MROWS (B_SZ * LSEQ) /* 8192 */

__device__ __forceinline__ float ldf(const float* p) { return *p; }
__device__ __forceinline__ float ldf(const __hip_bfloat16* p) { return __bfloat162float(*p); }
__device__ __forceinline__ void store_out(float* p, float v) { *p = v; }
__device__ __forceinline__ void store_out(__hip_bfloat16* p, float v) { *p = __float2bfloat16(v); }

// ---------------- dtype probe ----------------
// Looks at low 16 bits of the first 256 dword slots of x. bf16 storage -> these
// are bf16 N(0,1) values, exponent field <=130 (|v|<16) ~always. fp32 storage ->
// these are mantissa bits, exponent field uniform, ~51% <=130.
// flag: 1 = inputs are bf16, 0 = inputs are fp32.
__global__ void probe_kernel(const unsigned short* __restrict__ p, int* __restrict__ flag) {
  int lane = threadIdx.x;  // 64 lanes
  int sane = 0;
#pragma unroll
  for (int j = 0; j < 4; j++) {
    unsigned short lo = p[(lane * 4 + j) * 2];  // low half of dword slot
    int e = (lo >> 7) & 0xFF;
    sane += (e <= 130) ? 1 : 0;
  }
  sane += __shfl_xor(sane, 1, 64);
  sane += __shfl_xor(sane, 2, 64);
  sane += __shfl_xor(sane, 4, 64);
  sane += __shfl_xor(sane, 8, 64);
  sane += __shfl_xor(sane, 16, 64);
  sane += __shfl_xor(sane, 32, 64);
  if (lane == 0) *flag = (sane >= 220) ? 1 : 0;
}

// ---------------- tiled vector GEMM: C[M,N] = A[M,K] @ B[K,N] (+bias) ----------------
// 64x64 tile, 256 threads, 4x4 microtile, BK=16.
template <typename TA, typename TB, typename TOUT>
__global__ __launch_bounds__(256) void gemm_kernel(
    const int* __restrict__ flag, int want,
    const TA* __restrict__ A, const TB* __restrict__ Bm,
    const TB* __restrict__ bias, TOUT* __restrict__ C,
    int M, int N, int K) {
  if (*flag != want) return;
  __shared__ float As[16][65];
  __shared__ float Bs[16][65];
  const int tid = threadIdx.x;
  const int tx = tid & 15, ty = tid >> 4;
  const int m0 = blockIdx.y * 64, n0 = blockIdx.x * 64;
  float acc[4][4] = {};
  for (int k0 = 0; k0 < K; k0 += 16) {
    {
      int m_l = tid >> 2;
      int k_l = (tid & 3) * 4;
      const TA* ap = A + (size_t)(m0 + m_l) * K + k0 + k_l;
#pragma unroll
      for (int i = 0; i < 4; i++) As[k_l + i][m_l] = ldf(ap + i);
    }
    {
      int k_l = tid >> 4;
      int n_l = (tid & 15) * 4;
      const TB* bp = Bm + (size_t)(k0 + k_l) * N + n0 + n_l;
#pragma unroll
      for (int i = 0; i < 4; i++) Bs[k_l][n_l + i] = ldf(bp + i);
    }
    __syncthreads();
#pragma unroll
    for (int kk = 0; kk < 16; kk++) {
      float a[4], b[4];
#pragma unroll
      for (int i = 0; i < 4; i++) a[i] = As[kk][ty * 4 + i];
#pragma unroll
      for (int j = 0; j < 4; j++) b[j] = Bs[kk][tx * 4 + j];
#pragma unroll
      for (int i = 0; i < 4; i++)
#pragma unroll
        for (int j = 0; j < 4; j++) acc[i][j] += a[i] * b[j];
    }
    __syncthreads();
  }
#pragma unroll
  for (int i = 0; i < 4; i++) {
    size_t m = (size_t)m0 + ty * 4 + i;
#pragma unroll
    for (int j = 0; j < 4; j++) {
      int n = n0 + tx * 4 + j;
      float v = acc[i][j];
      if (bias) v += ldf(bias + n);
      store_out(&C[m * N + n], v);
    }
  }
}

// ---------------- depthwise conv (k=4, SAME: pad_low=1) + SiLU, both halves ----------------
template <typename TW>
__global__ __launch_bounds__(256) void conv_silu_kernel(
    const int* __restrict__ flag, int want,
    const float* __restrict__ xz,
    const TW* __restrict__ wx, const TW* __restrict__ bx,
    const TW* __restrict__ wz, const TW* __restrict__ bz,
    float* __restrict__ xs_conv, __hip_bfloat16* __restrict__ cat) {
  if (*flag != want) return;
  int gid = blockIdx.x * 256 + threadIdx.x;  // M*1024 threads
  int c = gid & 1023;
  int m = gid >> 10;
  int t = m & (LSEQ - 1);
  float ax = ldf(bx + c);
  float az = ldf(bz + c);
#pragma unroll
  for (int j = 0; j < 4; j++) {
    int tt = t - 1 + j;
    if (tt < 0 || tt >= LSEQ) continue;
    size_t row = (size_t)(m - t + tt);
    float vx = xz[row * DI + c];
    float vz = xz[row * DI + DH + c];
    ax += ldf(wx + j * DH + c) * vx;
    az += ldf(wz + j * DH + c) * vz;
  }
  float sx = ax / (1.f + __expf(-ax));
  float sz = az / (1.f + __expf(-az));
  xs_conv[(size_t)m * DH + c] = sx;
  cat[(size_t)m * DI + DH + c] = __float2bfloat16(sz);
}

// ---------------- x_dbl = xs_conv @ W_xdbl  (K=1024, N=96) ----------------
template <typename TW>
__global__ __launch_bounds__(128) void xdbl_kernel(
    const int* __restrict__ flag, int want,
    const float* __restrict__ xs_conv, const TW* __restrict__ W,
    float* __restrict__ xdbl) {
  if (*flag != want) return;
  __shared__ float xs_s[4][128];
  int r = threadIdx.x;
  int m0 = blockIdx.x * 4;
  float acc[4] = {0.f, 0.f, 0.f, 0.f};
  for (int k0 = 0; k0 < DH; k0 += 128) {
#pragma unroll
    for (int i = 0; i < 4; i++) {
      int e = threadIdx.x + i * 128;
      xs_s[e >> 7][e & 127] = xs_conv[(size_t)(m0 + (e >> 7)) * DH + k0 + (e & 127)];
    }
    __syncthreads();
    if (r < RTOT) {
      for (int kk = 0; kk < 128; kk++) {
        float w = ldf(W + (size_t)(k0 + kk) * RTOT + r);
#pragma unroll
        for (int i = 0; i < 4; i++) acc[i] += w * xs_s[i][kk];
      }
    }
    __syncthreads();
  }
  if (r < RTOT) {
#pragma unroll
    for (int i = 0; i < 4; i++) xdbl[(size_t)(m0 + i) * RTOT + r] = acc[i];
  }
}

// ---------------- delta = softplus(dt_low @ W_dt + 2*inv_dt)  (K=64, N=1024) ----------------
template <typename TW>
__global__ __launch_bounds__(256) void delta_kernel(
    const int* __restrict__ flag, int want,
    const float* __restrict__ xdbl, const TW* __restrict__ Wdt,
    const TW* __restrict__ inv_dt, float* __restrict__ delta) {
  if (*flag != want) return;
  int m = blockIdx.x >> 2;
  int d = ((blockIdx.x & 3) << 8) + threadIdx.x;
  __shared__ float xr[DTR];
  if (threadIdx.x < DTR) xr[threadIdx.x] = xdbl[(size_t)m * RTOT + threadIdx.x];
  __syncthreads();
  float acc = 0.f;
#pragma unroll 8
  for (int rr = 0; rr < DTR; rr++) acc += xr[rr] * ldf(Wdt + (size_t)rr * DH + d);
  float v = acc + 2.f * ldf(inv_dt + d);
  float sp = (v > 0.f) ? (v + log1pf(__expf(-v))) : log1pf(__expf(v));
  delta[(size_t)m * DH + d] = sp;
}

// ---------------- selective scan ----------------
template <typename TW>
__global__ __launch_bounds__(256) void scan_kernel(
    const int* __restrict__ flag, int want,
    const float* __restrict__ delta, const float* __restrict__ u,
    const float* __restrict__ xdbl, const TW* __restrict__ Dvec,
    __hip_bfloat16* __restrict__ cat) {
  if (*flag != want) return;
  const int b = blockIdx.x >> 6;
  const int d0 = (blockIdx.x & 63) * 16;
  const int tid = threadIdx.x;
  const int dl = tid >> 4;
  const int n = tid & 15;
  __shared__ float sd[64][16], su[64][16], sB[64][16], sC[64][16], sy[64][16];
  __shared__ float sD[16];
  if (tid < 16) sD[tid] = ldf(Dvec + d0 + tid);
  const float Acoef = -(float)(n + 1);
  float h = 0.f;
  const size_t base_m = (size_t)b * LSEQ;
  for (int t0 = 0; t0 < LSEQ; t0 += 64) {
#pragma unroll
    for (int it = 0; it < 4; it++) {
      int e = tid + it * 256;
      int tl = e >> 4, dd = e & 15;
      size_t row = base_m + t0 + tl;
      sd[tl][dd] = delta[row * DH + d0 + dd];
      su[tl][dd] = u[row * DH + d0 + dd];
      sB[tl][dd] = xdbl[row * RTOT + DTR + dd];
      sC[tl][dd] = xdbl[row * RTOT + DTR + DS + dd];
    }
    __syncthreads();
    for (int t = 0; t < 64; t++) {
      float dt = sd[t][dl];
      float ut = su[t][dl];
      float bt = sB[t][n];
      float ct = sC[t][n];
      float dA = __expf(dt * Acoef);
      h = dA * h + dt * ut * bt;
      float p = h * ct;
      p += __shfl_xor(p, 1, 64);
      p += __shfl_xor(p, 2, 64);
      p += __shfl_xor(p, 4, 64);
      p += __shfl_xor(p, 8, 64);
      if (n == 0) sy[t][dl] = p + ut * sD[dl];
    }
    __syncthreads();
#pragma unroll
    for (int it = 0; it < 4; it++) {
      int e = tid + it * 256;
      int tl = e >> 4, dd = e & 15;
      size_t row = base_m + t0 + tl;
      cat[row * DI + d0 + dd] = __float2bfloat16(sy[tl][dd]);
    }
    // next load phase writes sd/su/sB/sC only; sy rewritten after that phase's
    // __syncthreads, so no extra barrier needed here.
  }
}

extern "C" void kernel_launch(void* const* d_in, const int* in_sizes, int n_in,
                              void* d_out, int out_size, void* d_ws, size_t ws_size,
                              hipStream_t stream) {
  char* ws = (char*)d_ws;
  // layout: [0,64MB): xz fp32 [8192][2048]; delta fp32 [8192][1024] aliases [0,32MB) after conv
  // [64MB,96MB): xs_conv fp32 [8192][1024]
  // [96MB,128MB): cat bf16 [8192][2048]  (y cols 0..1023, z cols 1024..2047)
  // [128MB,131MB): x_dbl fp32 [8192][96]
  // [131MB]: dtype flag (int)
  float* xz        = (float*)(ws);
  float* delta     = (float*)(ws);
  float* xs_conv   = (float*)(ws + ((size_t)64 << 20));
  __hip_bfloat16* cat = (__hip_bfloat16*)(ws + ((size_t)96 << 20));
  float* xdbl      = (float*)(ws + ((size_t)128 << 20));
  int* flag        = (int*)(ws + ((size_t)131 << 20));

  probe_kernel<<<1, 64, 0, stream>>>((const unsigned short*)d_in[0], flag);

  // ---- bf16 input path (want=1) ----
  {
    const __hip_bfloat16* x      = (const __hip_bfloat16*)d_in[0];
    const __hip_bfloat16* W_in   = (const __hip_bfloat16*)d_in[1];
    const __hip_bfloat16* conv_xw = (const __hip_bfloat16*)d_in[2];
    const __hip_bfloat16* conv_xb = (const __hip_bfloat16*)d_in[3];
    const __hip_bfloat16* conv_zw = (const __hip_bfloat16*)d_in[4];
    const __hip_bfloat16* conv_zb = (const __hip_bfloat16*)d_in[5];
    const __hip_bfloat16* W_xdbl = (const __hip_bfloat16*)d_in[6];
    const __hip_bfloat16* W_dt   = (const __hip_bfloat16*)d_in[7];
    const __hip_bfloat16* inv_dt = (const __hip_bfloat16*)d_in[8];
    const __hip_bfloat16* Dvec   = (const __hip_bfloat16*)d_in[9];
    const __hip_bfloat16* W_out  = (const __hip_bfloat16*)d_in[10];
    const __hip_bfloat16* b_out  = (const __hip_bfloat16*)d_in[11];

    gemm_kernel<__hip_bfloat16, __hip_bfloat16, float>
        <<<dim3(DI / 64, MROWS / 64), 256, 0, stream>>>(
        flag, 1, x, W_in, (const __hip_bfloat16*)nullptr, xz, MROWS, DI, DM);
    conv_silu_kernel<__hip_bfloat16><<<(MROWS * DH) / 256, 256, 0, stream>>>(
        flag, 1, xz, conv_xw, conv_xb, conv_zw, conv_zb, xs_conv, cat);
    xdbl_kernel<__hip_bfloat16><<<MROWS / 4, 128, 0, stream>>>(
        flag, 1, xs_conv, W_xdbl, xdbl);
    delta_kernel<__hip_bfloat16><<<MROWS * 4, 256, 0, stream>>>(
        flag, 1, xdbl, W_dt, inv_dt, delta);
    scan_kernel<__hip_bfloat16><<<256, 256, 0, stream>>>(
        flag, 1, delta, xs_conv, xdbl, Dvec, cat);
    gemm_kernel<__hip_bfloat16, __hip_bfloat16, __hip_bfloat16>
        <<<dim3(DM / 64, MROWS / 64), 256, 0, stream>>>(
        flag, 1, cat, W_out, b_out, (__hip_bfloat16*)d_out, MROWS, DM, DI);
  }

  // ---- fp32 input path (want=0) ----
  {
    const float* x      = (const float*)d_in[0];
    const float* W_in   = (const float*)d_in[1];
    const float* conv_xw = (const float*)d_in[2];
    const float* conv_xb = (const float*)d_in[3];
    const float* conv_zw = (const float*)d_in[4];
    const float* conv_zb = (const float*)d_in[5];
    const float* W_xdbl = (const float*)d_in[6];
    const float* W_dt   = (const float*)d_in[7];
    const float* inv_dt = (const float*)d_in[8];
    const float* Dvec   = (const float*)d_in[9];
    const float* W_out  = (const float*)d_in[10];
    const float* b_out  = (const float*)d_in[11];

    gemm_kernel<float, float, float>
        <<<dim3(DI / 64, MROWS / 64), 256, 0, stream>>>(
        flag, 0, x, W_in, (const float*)nullptr, xz, MROWS, DI, DM);
    conv_silu_kernel<float><<<(MROWS * DH) / 256, 256, 0, stream>>>(
        flag, 0, xz, conv_xw, conv_xb, conv_zw, conv_zb, xs_conv, cat);
    xdbl_kernel<float><<<MROWS / 4, 128, 0, stream>>>(
        flag, 0, xs_conv, W_xdbl, xdbl);
    delta_kernel<float><<<MROWS * 4, 256, 0, stream>>>(
        flag, 0, xdbl, W_dt, inv_dt, delta);
    scan_kernel<float><<<256, 256, 0, stream>>>(
        flag, 0, delta, xs_conv, xdbl, Dvec, cat);
    gemm_kernel<__hip_bfloat16, float, float>
        <<<dim3(DM / 64, MROWS / 64), 256, 0, stream>>>(
        flag, 0, cat, W_out, b_out, (float*)d_out, MROWS, DM, DI);
  }
}

// Round 3
// 941.262 us; speedup vs baseline: 2.1595x; 2.1595x over previous
//
#include <hip/hip_runtime.h>
#include <hip/hip_bf16.h>
#include <math.h>

#define B_SZ 4
#define LSEQ 2048
#define DM 1024
#define DI 2048
#define DH 1024
#define DS 16
#define DTR 64
#define RTOT 96
#define MROWS (B_SZ * LSEQ) /* 8192 */

// MFMA GEMM tile config
#define BM 128
#define BN 128
#define BKT 32
#define LDT 56 /* LDS row stride in bf16 elems (112B): uniform bank coverage for b128 */

typedef short bf8_t __attribute__((ext_vector_type(8)));
typedef float f4_t __attribute__((ext_vector_type(4)));

__device__ __forceinline__ float ldf(const float* p) { return *p; }
__device__ __forceinline__ float ldf(const __hip_bfloat16* p) { return __bfloat162float(*p); }
__device__ __forceinline__ void store_out(float* p, float v) { *p = v; }
__device__ __forceinline__ void store_out(__hip_bfloat16* p, float v) { *p = __float2bfloat16(v); }

__device__ __forceinline__ unsigned short f2bfbits(float v) {
  __hip_bfloat16 h = __float2bfloat16(v);
  return *(unsigned short*)&h;
}
__device__ __forceinline__ unsigned short bfbits(const __hip_bfloat16* p) {
  return *(const unsigned short*)p;
}
__device__ __forceinline__ unsigned short bfbits(const float* p) { return f2bfbits(*p); }

// load 8 contiguous elements as bf16 bit patterns
__device__ __forceinline__ void ld8(const __hip_bfloat16* p, unsigned short* d) {
  *(uint4*)d = *(const uint4*)p;
}
__device__ __forceinline__ void ld8(const float* p, unsigned short* d) {
  const float4 a = ((const float4*)p)[0];
  const float4 b = ((const float4*)p)[1];
  d[0] = f2bfbits(a.x); d[1] = f2bfbits(a.y); d[2] = f2bfbits(a.z); d[3] = f2bfbits(a.w);
  d[4] = f2bfbits(b.x); d[5] = f2bfbits(b.y); d[6] = f2bfbits(b.z); d[7] = f2bfbits(b.w);
}

// ---------------- dtype probe (1 = bf16 inputs, 0 = fp32 inputs) ----------------
__global__ void probe_kernel(const unsigned short* __restrict__ p, int* __restrict__ flag) {
  int lane = threadIdx.x;  // 64 lanes
  int sane = 0;
#pragma unroll
  for (int j = 0; j < 4; j++) {
    unsigned short lo = p[(lane * 4 + j) * 2];
    int e = (lo >> 7) & 0xFF;
    sane += (e <= 130) ? 1 : 0;
  }
  sane += __shfl_xor(sane, 1, 64);
  sane += __shfl_xor(sane, 2, 64);
  sane += __shfl_xor(sane, 4, 64);
  sane += __shfl_xor(sane, 8, 64);
  sane += __shfl_xor(sane, 16, 64);
  sane += __shfl_xor(sane, 32, 64);
  if (lane == 0) *flag = (sane >= 220) ? 1 : 0;
}

// ---------------- MFMA GEMM: C[M,N] = A[M,K] @ B[K,N] (+bias) ----------------
// 128x128 block tile, BK=32, 256 threads = 4 waves (2x2), wave tile 64x64 =
// 4x4 mfma_f32_16x16x32_bf16. A staged [m][k], B transposed to [n][k].
template <typename TA, typename TB, typename TOUT>
__global__ __launch_bounds__(256) void mfma_gemm_kernel(
    const int* __restrict__ flag, int want,
    const TA* __restrict__ A, const TB* __restrict__ Bm,
    const TB* __restrict__ bias, TOUT* __restrict__ C,
    int M, int N, int K) {
  if (*flag != want) return;
  __shared__ __align__(16) unsigned short As[BM * LDT];
  __shared__ __align__(16) unsigned short Bs[BN * LDT];
  const int tid = threadIdx.x;
  const int lane = tid & 63;
  const int wave = tid >> 6;
  const int quad = lane >> 4;
  const int l16 = lane & 15;
  const int wm = (wave & 1) * 64;
  const int wn = (wave >> 1) * 64;
  const int m0 = blockIdx.y * BM;
  const int n0 = blockIdx.x * BN;

  f4_t acc[4][4] = {};

  for (int k0 = 0; k0 < K; k0 += BKT) {
    // stage A: 128 rows x 32 k, 512 16B-chunks, 2 per thread
#pragma unroll
    for (int i = 0; i < 2; i++) {
      int task = tid + i * 256;
      int m = task >> 2;
      int seg = task & 3;
      unsigned short tmp[8];
      ld8(A + (size_t)(m0 + m) * K + k0 + seg * 8, tmp);
      *(uint4*)&As[m * LDT + seg * 8] = *(uint4*)tmp;
    }
    // stage B transposed: Bs[n][k] <- B[k][n]
#pragma unroll
    for (int i = 0; i < 2; i++) {
      int task = tid + i * 256;
      int n = task & 127;
      int seg = task >> 7;
      unsigned short tmp[8];
#pragma unroll
      for (int j = 0; j < 8; j++)
        tmp[j] = bfbits(Bm + (size_t)(k0 + seg * 8 + j) * N + n0 + n);
      *(uint4*)&Bs[n * LDT + seg * 8] = *(uint4*)tmp;
    }
    __syncthreads();

    bf8_t af[4], bfr[4];
#pragma unroll
    for (int ti = 0; ti < 4; ti++)
      af[ti] = *(const bf8_t*)&As[(wm + ti * 16 + l16) * LDT + quad * 8];
#pragma unroll
    for (int tj = 0; tj < 4; tj++)
      bfr[tj] = *(const bf8_t*)&Bs[(wn + tj * 16 + l16) * LDT + quad * 8];
#pragma unroll
    for (int ti = 0; ti < 4; ti++)
#pragma unroll
      for (int tj = 0; tj < 4; tj++)
        acc[ti][tj] = __builtin_amdgcn_mfma_f32_16x16x32_bf16(
            af[ti], bfr[tj], acc[ti][tj], 0, 0, 0);
    __syncthreads();
  }

  // epilogue: C/D layout col=lane&15, row=quad*4+reg
#pragma unroll
  for (int ti = 0; ti < 4; ti++) {
#pragma unroll
    for (int tj = 0; tj < 4; tj++) {
      int col = n0 + wn + tj * 16 + l16;
      float bv = bias ? ldf(bias + col) : 0.f;
#pragma unroll
      for (int r = 0; r < 4; r++) {
        int row = m0 + wm + ti * 16 + quad * 4 + r;
        store_out(&C[(size_t)row * N + col], acc[ti][tj][r] + bv);
      }
    }
  }
}

// ---------------- depthwise conv (k=4, SAME: pad_low=1) + SiLU, both halves ----------------
template <typename TW>
__global__ __launch_bounds__(256) void conv_silu_kernel(
    const int* __restrict__ flag, int want,
    const float* __restrict__ xz,
    const TW* __restrict__ wx, const TW* __restrict__ bx,
    const TW* __restrict__ wz, const TW* __restrict__ bz,
    float* __restrict__ xs_conv, __hip_bfloat16* __restrict__ cat) {
  if (*flag != want) return;
  int gid = blockIdx.x * 256 + threadIdx.x;  // M*1024 threads
  int c = gid & 1023;
  int m = gid >> 10;
  int t = m & (LSEQ - 1);
  float ax = ldf(bx + c);
  float az = ldf(bz + c);
#pragma unroll
  for (int j = 0; j < 4; j++) {
    int tt = t - 1 + j;
    if (tt < 0 || tt >= LSEQ) continue;
    size_t row = (size_t)(m - t + tt);
    float vx = xz[row * DI + c];
    float vz = xz[row * DI + DH + c];
    ax += ldf(wx + j * DH + c) * vx;
    az += ldf(wz + j * DH + c) * vz;
  }
  float sx = ax / (1.f + __expf(-ax));
  float sz = az / (1.f + __expf(-az));
  xs_conv[(size_t)m * DH + c] = sx;
  cat[(size_t)m * DI + DH + c] = __float2bfloat16(sz);
}

// ---------------- x_dbl = xs_conv @ W_xdbl  (K=1024, N=96) ----------------
template <typename TW>
__global__ __launch_bounds__(128) void xdbl_kernel(
    const int* __restrict__ flag, int want,
    const float* __restrict__ xs_conv, const TW* __restrict__ W,
    float* __restrict__ xdbl) {
  if (*flag != want) return;
  __shared__ float xs_s[4][128];
  int r = threadIdx.x;
  int m0 = blockIdx.x * 4;
  float acc[4] = {0.f, 0.f, 0.f, 0.f};
  for (int k0 = 0; k0 < DH; k0 += 128) {
#pragma unroll
    for (int i = 0; i < 4; i++) {
      int e = threadIdx.x + i * 128;
      xs_s[e >> 7][e & 127] = xs_conv[(size_t)(m0 + (e >> 7)) * DH + k0 + (e & 127)];
    }
    __syncthreads();
    if (r < RTOT) {
      for (int kk = 0; kk < 128; kk++) {
        float w = ldf(W + (size_t)(k0 + kk) * RTOT + r);
#pragma unroll
        for (int i = 0; i < 4; i++) acc[i] += w * xs_s[i][kk];
      }
    }
    __syncthreads();
  }
  if (r < RTOT) {
#pragma unroll
    for (int i = 0; i < 4; i++) xdbl[(size_t)(m0 + i) * RTOT + r] = acc[i];
  }
}

// ---------------- delta = softplus(dt_low @ W_dt + 2*inv_dt)  (K=64, N=1024) ----------------
template <typename TW>
__global__ __launch_bounds__(256) void delta_kernel(
    const int* __restrict__ flag, int want,
    const float* __restrict__ xdbl, const TW* __restrict__ Wdt,
    const TW* __restrict__ inv_dt, float* __restrict__ delta) {
  if (*flag != want) return;
  int m = blockIdx.x >> 2;
  int d = ((blockIdx.x & 3) << 8) + threadIdx.x;
  __shared__ float xr[DTR];
  if (threadIdx.x < DTR) xr[threadIdx.x] = xdbl[(size_t)m * RTOT + threadIdx.x];
  __syncthreads();
  float acc = 0.f;
#pragma unroll 8
  for (int rr = 0; rr < DTR; rr++) acc += xr[rr] * ldf(Wdt + (size_t)rr * DH + d);
  float v = acc + 2.f * ldf(inv_dt + d);
  float sp = (v > 0.f) ? (v + log1pf(__expf(-v))) : log1pf(__expf(v));
  delta[(size_t)m * DH + d] = sp;
}

// ---------------- selective scan ----------------
template <typename TW>
__global__ __launch_bounds__(256) void scan_kernel(
    const int* __restrict__ flag, int want,
    const float* __restrict__ delta, const float* __restrict__ u,
    const float* __restrict__ xdbl, const TW* __restrict__ Dvec,
    __hip_bfloat16* __restrict__ cat) {
  if (*flag != want) return;
  const int b = blockIdx.x >> 6;
  const int d0 = (blockIdx.x & 63) * 16;
  const int tid = threadIdx.x;
  const int dl = tid >> 4;
  const int n = tid & 15;
  __shared__ float sd[64][16], su[64][16], sB[64][16], sC[64][16], sy[64][16];
  __shared__ float sD[16];
  if (tid < 16) sD[tid] = ldf(Dvec + d0 + tid);
  const float Acoef = -(float)(n + 1);
  float h = 0.f;
  const size_t base_m = (size_t)b * LSEQ;
  for (int t0 = 0; t0 < LSEQ; t0 += 64) {
#pragma unroll
    for (int it = 0; it < 4; it++) {
      int e = tid + it * 256;
      int tl = e >> 4, dd = e & 15;
      size_t row = base_m + t0 + tl;
      sd[tl][dd] = delta[row * DH + d0 + dd];
      su[tl][dd] = u[row * DH + d0 + dd];
      sB[tl][dd] = xdbl[row * RTOT + DTR + dd];
      sC[tl][dd] = xdbl[row * RTOT + DTR + DS + dd];
    }
    __syncthreads();
    for (int t = 0; t < 64; t++) {
      float dt = sd[t][dl];
      float ut = su[t][dl];
      float bt = sB[t][n];
      float ct = sC[t][n];
      float dA = __expf(dt * Acoef);
      h = dA * h + dt * ut * bt;
      float p = h * ct;
      p += __shfl_xor(p, 1, 64);
      p += __shfl_xor(p, 2, 64);
      p += __shfl_xor(p, 4, 64);
      p += __shfl_xor(p, 8, 64);
      if (n == 0) sy[t][dl] = p + ut * sD[dl];
    }
    __syncthreads();
#pragma unroll
    for (int it = 0; it < 4; it++) {
      int e = tid + it * 256;
      int tl = e >> 4, dd = e & 15;
      size_t row = base_m + t0 + tl;
      cat[row * DI + d0 + dd] = __float2bfloat16(sy[tl][dd]);
    }
  }
}

extern "C" void kernel_launch(void* const* d_in, const int* in_sizes, int n_in,
                              void* d_out, int out_size, void* d_ws, size_t ws_size,
                              hipStream_t stream) {
  char* ws = (char*)d_ws;
  // layout: [0,64MB): xz fp32 [8192][2048]; delta fp32 aliases [0,32MB) after conv
  // [64MB,96MB): xs_conv fp32 [8192][1024]
  // [96MB,128MB): cat bf16 [8192][2048]  (y cols 0..1023, z cols 1024..2047)
  // [128MB,131MB): x_dbl fp32 [8192][96]
  // [131MB]: dtype flag (int)
  float* xz        = (float*)(ws);
  float* delta     = (float*)(ws);
  float* xs_conv   = (float*)(ws + ((size_t)64 << 20));
  __hip_bfloat16* cat = (__hip_bfloat16*)(ws + ((size_t)96 << 20));
  float* xdbl      = (float*)(ws + ((size_t)128 << 20));
  int* flag        = (int*)(ws + ((size_t)131 << 20));

  probe_kernel<<<1, 64, 0, stream>>>((const unsigned short*)d_in[0], flag);

  // ---- bf16 input path (want=1) ----
  {
    const __hip_bfloat16* x      = (const __hip_bfloat16*)d_in[0];
    const __hip_bfloat16* W_in   = (const __hip_bfloat16*)d_in[1];
    const __hip_bfloat16* conv_xw = (const __hip_bfloat16*)d_in[2];
    const __hip_bfloat16* conv_xb = (const __hip_bfloat16*)d_in[3];
    const __hip_bfloat16* conv_zw = (const __hip_bfloat16*)d_in[4];
    const __hip_bfloat16* conv_zb = (const __hip_bfloat16*)d_in[5];
    const __hip_bfloat16* W_xdbl = (const __hip_bfloat16*)d_in[6];
    const __hip_bfloat16* W_dt   = (const __hip_bfloat16*)d_in[7];
    const __hip_bfloat16* inv_dt = (const __hip_bfloat16*)d_in[8];
    const __hip_bfloat16* Dvec   = (const __hip_bfloat16*)d_in[9];
    const __hip_bfloat16* W_out  = (const __hip_bfloat16*)d_in[10];
    const __hip_bfloat16* b_out  = (const __hip_bfloat16*)d_in[11];

    mfma_gemm_kernel<__hip_bfloat16, __hip_bfloat16, float>
        <<<dim3(DI / BN, MROWS / BM), 256, 0, stream>>>(
        flag, 1, x, W_in, (const __hip_bfloat16*)nullptr, xz, MROWS, DI, DM);
    conv_silu_kernel<__hip_bfloat16><<<(MROWS * DH) / 256, 256, 0, stream>>>(
        flag, 1, xz, conv_xw, conv_xb, conv_zw, conv_zb, xs_conv, cat);
    xdbl_kernel<__hip_bfloat16><<<MROWS / 4, 128, 0, stream>>>(
        flag, 1, xs_conv, W_xdbl, xdbl);
    delta_kernel<__hip_bfloat16><<<MROWS * 4, 256, 0, stream>>>(
        flag, 1, xdbl, W_dt, inv_dt, delta);
    scan_kernel<__hip_bfloat16><<<256, 256, 0, stream>>>(
        flag, 1, delta, xs_conv, xdbl, Dvec, cat);
    mfma_gemm_kernel<__hip_bfloat16, __hip_bfloat16, __hip_bfloat16>
        <<<dim3(DM / BN, MROWS / BM), 256, 0, stream>>>(
        flag, 1, cat, W_out, b_out, (__hip_bfloat16*)d_out, MROWS, DM, DI);
  }

  // ---- fp32 input path (want=0) ----
  {
    const float* x      = (const float*)d_in[0];
    const float* W_in   = (const float*)d_in[1];
    const float* conv_xw = (const float*)d_in[2];
    const float* conv_xb = (const float*)d_in[3];
    const float* conv_zw = (const float*)d_in[4];
    const float* conv_zb = (const float*)d_in[5];
    const float* W_xdbl = (const float*)d_in[6];
    const float* W_dt   = (const float*)d_in[7];
    const float* inv_dt = (const float*)d_in[8];
    const float* Dvec   = (const float*)d_in[9];
    const float* W_out  = (const float*)d_in[10];
    const float* b_out  = (const float*)d_in[11];

    mfma_gemm_kernel<float, float, float>
        <<<dim3(DI / BN, MROWS / BM), 256, 0, stream>>>(
        flag, 0, x, W_in, (const float*)nullptr, xz, MROWS, DI, DM);
    conv_silu_kernel<float><<<(MROWS * DH) / 256, 256, 0, stream>>>(
        flag, 0, xz, conv_xw, conv_xb, conv_zw, conv_zb, xs_conv, cat);
    xdbl_kernel<float><<<MROWS / 4, 128, 0, stream>>>(
        flag, 0, xs_conv, W_xdbl, xdbl);
    delta_kernel<float><<<MROWS * 4, 256, 0, stream>>>(
        flag, 0, xdbl, W_dt, inv_dt, delta);
    scan_kernel<float><<<256, 256, 0, stream>>>(
        flag, 0, delta, xs_conv, xdbl, Dvec, cat);
    mfma_gemm_kernel<__hip_bfloat16, float, float>
        <<<dim3(DM / BN, MROWS / BM), 256, 0, stream>>>(
        flag, 0, cat, W_out, b_out, (float*)d_out, MROWS, DM, DI);
  }
}

// Round 4
// 562.415 us; speedup vs baseline: 3.6142x; 1.6736x over previous
//
#include <hip/hip_runtime.h>
#include <hip/hip_bf16.h>
#include <math.h>

#define B_SZ 4
#define LSEQ 2048
#define DM 1024
#define DI 2048
#define DH 1024
#define DS 16
#define DTR 64
#define RTOT 96
#define MROWS (B_SZ * LSEQ) /* 8192 */

// MFMA GEMM tile config
#define BM 128
#define BN 128
#define BKT 32
#define LDT 56 /* LDS row stride in bf16 elems (112B) */

// scan chunking
#define NCH 32
#define CHUNK 64 /* LSEQ / NCH */

typedef short bf8_t __attribute__((ext_vector_type(8)));
typedef float f4_t __attribute__((ext_vector_type(4)));

__device__ __forceinline__ float ldf(const float* p) { return *p; }
__device__ __forceinline__ float ldf(const __hip_bfloat16* p) { return __bfloat162float(*p); }
__device__ __forceinline__ void store_out(float* p, float v) { *p = v; }
__device__ __forceinline__ void store_out(__hip_bfloat16* p, float v) { *p = __float2bfloat16(v); }

__device__ __forceinline__ unsigned short f2bfbits(float v) {
  __hip_bfloat16 h = __float2bfloat16(v);
  return *(unsigned short*)&h;
}
__device__ __forceinline__ unsigned short bfbits(const __hip_bfloat16* p) {
  return *(const unsigned short*)p;
}
__device__ __forceinline__ unsigned short bfbits(const float* p) { return f2bfbits(*p); }

__device__ __forceinline__ void ld8(const __hip_bfloat16* p, unsigned short* d) {
  *(uint4*)d = *(const uint4*)p;
}
__device__ __forceinline__ void ld8(const float* p, unsigned short* d) {
  const float4 a = ((const float4*)p)[0];
  const float4 b = ((const float4*)p)[1];
  d[0] = f2bfbits(a.x); d[1] = f2bfbits(a.y); d[2] = f2bfbits(a.z); d[3] = f2bfbits(a.w);
  d[4] = f2bfbits(b.x); d[5] = f2bfbits(b.y); d[6] = f2bfbits(b.z); d[7] = f2bfbits(b.w);
}

// ---------------- dtype probe (1 = bf16 inputs, 0 = fp32 inputs) ----------------
__global__ void probe_kernel(const unsigned short* __restrict__ p, int* __restrict__ flag) {
  int lane = threadIdx.x;  // 64 lanes
  int sane = 0;
#pragma unroll
  for (int j = 0; j < 4; j++) {
    unsigned short lo = p[(lane * 4 + j) * 2];
    int e = (lo >> 7) & 0xFF;
    sane += (e <= 130) ? 1 : 0;
  }
  sane += __shfl_xor(sane, 1, 64);
  sane += __shfl_xor(sane, 2, 64);
  sane += __shfl_xor(sane, 4, 64);
  sane += __shfl_xor(sane, 8, 64);
  sane += __shfl_xor(sane, 16, 64);
  sane += __shfl_xor(sane, 32, 64);
  if (lane == 0) *flag = (sane >= 220) ? 1 : 0;
}

// ---------------- MFMA GEMM: C[M,N] = A[M,K] @ B[K,N] (+bias) ----------------
template <typename TA, typename TB, typename TOUT>
__global__ __launch_bounds__(256) void mfma_gemm_kernel(
    const int* __restrict__ flag, int want,
    const TA* __restrict__ A, const TB* __restrict__ Bm,
    const TB* __restrict__ bias, TOUT* __restrict__ C,
    int M, int N, int K) {
  if (*flag != want) return;
  __shared__ __align__(16) unsigned short As[BM * LDT];
  __shared__ __align__(16) unsigned short Bs[BN * LDT];
  const int tid = threadIdx.x;
  const int lane = tid & 63;
  const int wave = tid >> 6;
  const int quad = lane >> 4;
  const int l16 = lane & 15;
  const int wm = (wave & 1) * 64;
  const int wn = (wave >> 1) * 64;
  const int m0 = blockIdx.y * BM;
  const int n0 = blockIdx.x * BN;

  f4_t acc[4][4] = {};

  for (int k0 = 0; k0 < K; k0 += BKT) {
#pragma unroll
    for (int i = 0; i < 2; i++) {
      int task = tid + i * 256;
      int m = task >> 2;
      int seg = task & 3;
      unsigned short tmp[8];
      ld8(A + (size_t)(m0 + m) * K + k0 + seg * 8, tmp);
      *(uint4*)&As[m * LDT + seg * 8] = *(uint4*)tmp;
    }
#pragma unroll
    for (int i = 0; i < 2; i++) {
      int task = tid + i * 256;
      int n = task & 127;
      int seg = task >> 7;
      unsigned short tmp[8];
#pragma unroll
      for (int j = 0; j < 8; j++)
        tmp[j] = bfbits(Bm + (size_t)(k0 + seg * 8 + j) * N + n0 + n);
      *(uint4*)&Bs[n * LDT + seg * 8] = *(uint4*)tmp;
    }
    __syncthreads();

    bf8_t af[4], bfr[4];
#pragma unroll
    for (int ti = 0; ti < 4; ti++)
      af[ti] = *(const bf8_t*)&As[(wm + ti * 16 + l16) * LDT + quad * 8];
#pragma unroll
    for (int tj = 0; tj < 4; tj++)
      bfr[tj] = *(const bf8_t*)&Bs[(wn + tj * 16 + l16) * LDT + quad * 8];
#pragma unroll
    for (int ti = 0; ti < 4; ti++)
#pragma unroll
      for (int tj = 0; tj < 4; tj++)
        acc[ti][tj] = __builtin_amdgcn_mfma_f32_16x16x32_bf16(
            af[ti], bfr[tj], acc[ti][tj], 0, 0, 0);
    __syncthreads();
  }

#pragma unroll
  for (int ti = 0; ti < 4; ti++) {
#pragma unroll
    for (int tj = 0; tj < 4; tj++) {
      int col = n0 + wn + tj * 16 + l16;
      float bv = bias ? ldf(bias + col) : 0.f;
#pragma unroll
      for (int r = 0; r < 4; r++) {
        int row = m0 + wm + ti * 16 + quad * 4 + r;
        store_out(&C[(size_t)row * N + col], acc[ti][tj][r] + bv);
      }
    }
  }
}

// ---------------- depthwise conv (k=4, SAME: pad_low=1) + SiLU, both halves ----------------
template <typename TW>
__global__ __launch_bounds__(256) void conv_silu_kernel(
    const int* __restrict__ flag, int want,
    const float* __restrict__ xz,
    const TW* __restrict__ wx, const TW* __restrict__ bx,
    const TW* __restrict__ wz, const TW* __restrict__ bz,
    float* __restrict__ xs_conv, __hip_bfloat16* __restrict__ cat) {
  if (*flag != want) return;
  int gid = blockIdx.x * 256 + threadIdx.x;  // M*1024 threads
  int c = gid & 1023;
  int m = gid >> 10;
  int t = m & (LSEQ - 1);
  float ax = ldf(bx + c);
  float az = ldf(bz + c);
#pragma unroll
  for (int j = 0; j < 4; j++) {
    int tt = t - 1 + j;
    if (tt < 0 || tt >= LSEQ) continue;
    size_t row = (size_t)(m - t + tt);
    float vx = xz[row * DI + c];
    float vz = xz[row * DI + DH + c];
    ax += ldf(wx + j * DH + c) * vx;
    az += ldf(wz + j * DH + c) * vz;
  }
  float sx = ax / (1.f + __expf(-ax));
  float sz = az / (1.f + __expf(-az));
  xs_conv[(size_t)m * DH + c] = sx;
  cat[(size_t)m * DI + DH + c] = __float2bfloat16(sz);
}

// ---------------- x_dbl = xs_conv @ W_xdbl  (K=1024, N=96) ----------------
template <typename TW>
__global__ __launch_bounds__(128) void xdbl_kernel(
    const int* __restrict__ flag, int want,
    const float* __restrict__ xs_conv, const TW* __restrict__ W,
    float* __restrict__ xdbl) {
  if (*flag != want) return;
  __shared__ float xs_s[4][128];
  int r = threadIdx.x;
  int m0 = blockIdx.x * 4;
  float acc[4] = {0.f, 0.f, 0.f, 0.f};
  for (int k0 = 0; k0 < DH; k0 += 128) {
#pragma unroll
    for (int i = 0; i < 4; i++) {
      int e = threadIdx.x + i * 128;
      xs_s[e >> 7][e & 127] = xs_conv[(size_t)(m0 + (e >> 7)) * DH + k0 + (e & 127)];
    }
    __syncthreads();
    if (r < RTOT) {
      for (int kk = 0; kk < 128; kk++) {
        float w = ldf(W + (size_t)(k0 + kk) * RTOT + r);
#pragma unroll
        for (int i = 0; i < 4; i++) acc[i] += w * xs_s[i][kk];
      }
    }
    __syncthreads();
  }
  if (r < RTOT) {
#pragma unroll
    for (int i = 0; i < 4; i++) xdbl[(size_t)(m0 + i) * RTOT + r] = acc[i];
  }
}

// ---------------- delta = softplus(dt_low @ W_dt + 2*inv_dt)  (K=64, N=1024) ----------------
template <typename TW>
__global__ __launch_bounds__(256) void delta_kernel(
    const int* __restrict__ flag, int want,
    const float* __restrict__ xdbl, const TW* __restrict__ Wdt,
    const TW* __restrict__ inv_dt, float* __restrict__ delta) {
  if (*flag != want) return;
  int m = blockIdx.x >> 2;
  int d = ((blockIdx.x & 3) << 8) + threadIdx.x;
  __shared__ float xr[DTR];
  if (threadIdx.x < DTR) xr[threadIdx.x] = xdbl[(size_t)m * RTOT + threadIdx.x];
  __syncthreads();
  float acc = 0.f;
#pragma unroll 8
  for (int rr = 0; rr < DTR; rr++) acc += xr[rr] * ldf(Wdt + (size_t)rr * DH + d);
  float v = acc + 2.f * ldf(inv_dt + d);
  float sp = (v > 0.f) ? (v + log1pf(__expf(-v))) : log1pf(__expf(v));
  delta[(size_t)m * DH + d] = sp;
}

// ---------------- chunked selective scan ----------------
// pass1: per-chunk scan from h=0. Thread owns one d-channel, 16 n-states in regs.
// grid (4 dgroups, NCH, B_SZ), 256 threads.
__global__ __launch_bounds__(256) void scan_pass1(
    const int* __restrict__ flag, int want,
    const float* __restrict__ delta, const float* __restrict__ u,
    const float* __restrict__ xdbl,
    float* __restrict__ Echunks, float* __restrict__ hp) {
  if (*flag != want) return;
  const int tid = threadIdx.x;
  const int d = blockIdx.x * 256 + tid;
  const int c = blockIdx.y, b = blockIdx.z;
  const int row0 = b * LSEQ + c * CHUNK;
  __shared__ float sBC[CHUNK][32];  // [t][0..15]=B, [16..31]=C
#pragma unroll
  for (int i = 0; i < 2; i++) {
    int task = tid + i * 256;
    int r = task >> 3, seg = task & 7;
    *(float4*)&sBC[r][seg * 4] =
        *(const float4*)&xdbl[(size_t)(row0 + r) * RTOT + DTR + seg * 4];
  }
  __syncthreads();
  float h[16];
#pragma unroll
  for (int n = 0; n < 16; n++) h[n] = 0.f;
  float E = 1.f;
  for (int t = 0; t < CHUNK; t++) {
    size_t off = (size_t)(row0 + t) * DH + d;
    float dt = delta[off], ut = u[off];
    float e = __expf(-dt);
    E *= e;
    float du = dt * ut;
    float p = 1.f;
#pragma unroll
    for (int n = 0; n < 16; n++) {
      p *= e;
      h[n] = fmaf(p, h[n], du * sBC[t][n]);
    }
  }
  Echunks[((size_t)c * B_SZ + b) * DH + d] = E;
#pragma unroll
  for (int n = 0; n < 16; n++)
    hp[(((size_t)c * B_SZ + b) * 16 + n) * DH + d] = h[n];
}

// pass2: sequential combine over chunks per (b,n,d). 65536 threads.
__global__ __launch_bounds__(256) void scan_pass2(
    const int* __restrict__ flag, int want,
    const float* __restrict__ Echunks, const float* __restrict__ hp,
    float* __restrict__ hs) {
  if (*flag != want) return;
  int t = blockIdx.x * 256 + threadIdx.x;
  int d = t & 1023;
  int n = (t >> 10) & 15;
  int b = t >> 14;
  float h = 0.f;
  const int k0 = n + 1;
  for (int c = 0; c < NCH; c++) {
    float E = Echunks[((size_t)c * B_SZ + b) * DH + d];
    float a = 1.f, base = E;
    int k = k0;
#pragma unroll
    for (int i = 0; i < 5; i++) {
      if (k & 1) a *= base;
      base *= base;
      k >>= 1;
    }
    size_t idx = (((size_t)c * B_SZ + b) * 16 + n) * DH + d;
    hs[idx] = h;
    h = fmaf(a, h, hp[idx]);
  }
}

// pass3: recompute chunk scan from h_start, emit y.
template <typename TW>
__global__ __launch_bounds__(256) void scan_pass3(
    const int* __restrict__ flag, int want,
    const float* __restrict__ delta, const float* __restrict__ u,
    const float* __restrict__ xdbl, const float* __restrict__ hs,
    const TW* __restrict__ Dvec, __hip_bfloat16* __restrict__ cat) {
  if (*flag != want) return;
  const int tid = threadIdx.x;
  const int d = blockIdx.x * 256 + tid;
  const int c = blockIdx.y, b = blockIdx.z;
  const int row0 = b * LSEQ + c * CHUNK;
  __shared__ float sBC[CHUNK][32];
#pragma unroll
  for (int i = 0; i < 2; i++) {
    int task = tid + i * 256;
    int r = task >> 3, seg = task & 7;
    *(float4*)&sBC[r][seg * 4] =
        *(const float4*)&xdbl[(size_t)(row0 + r) * RTOT + DTR + seg * 4];
  }
  __syncthreads();
  float h[16];
#pragma unroll
  for (int n = 0; n < 16; n++)
    h[n] = hs[(((size_t)c * B_SZ + b) * 16 + n) * DH + d];
  const float Dd = ldf(Dvec + d);
  for (int t = 0; t < CHUNK; t++) {
    size_t off = (size_t)(row0 + t) * DH + d;
    float dt = delta[off], ut = u[off];
    float e = __expf(-dt);
    float du = dt * ut;
    float p = 1.f, y = 0.f;
#pragma unroll
    for (int n = 0; n < 16; n++) {
      p *= e;
      h[n] = fmaf(p, h[n], du * sBC[t][n]);
      y = fmaf(h[n], sBC[t][16 + n], y);
    }
    y = fmaf(ut, Dd, y);
    cat[(size_t)(row0 + t) * DI + d] = __float2bfloat16(y);
  }
}

extern "C" void kernel_launch(void* const* d_in, const int* in_sizes, int n_in,
                              void* d_out, int out_size, void* d_ws, size_t ws_size,
                              hipStream_t stream) {
  char* ws = (char*)d_ws;
  // layout:
  // [0,64MB): xz fp32 [8192][2048]; delta fp32 aliases [0,32MB) after conv
  // [32MB,32.5MB): Echunks fp32 [NCH][4][1024]         (xz dead after conv)
  // [33MB,41MB):   hp fp32 [NCH][4][16][1024]
  // [42MB,50MB):   hs fp32 [NCH][4][16][1024]
  // [64MB,96MB): xs_conv fp32 [8192][1024]
  // [96MB,128MB): cat bf16 [8192][2048]  (y cols 0..1023, z cols 1024..2047)
  // [128MB,131MB): x_dbl fp32 [8192][96]
  // [131MB]: dtype flag (int)
  float* xz        = (float*)(ws);
  float* delta     = (float*)(ws);
  float* Echunks   = (float*)(ws + ((size_t)32 << 20));
  float* hp        = (float*)(ws + ((size_t)33 << 20));
  float* hs        = (float*)(ws + ((size_t)42 << 20));
  float* xs_conv   = (float*)(ws + ((size_t)64 << 20));
  __hip_bfloat16* cat = (__hip_bfloat16*)(ws + ((size_t)96 << 20));
  float* xdbl      = (float*)(ws + ((size_t)128 << 20));
  int* flag        = (int*)(ws + ((size_t)131 << 20));

  probe_kernel<<<1, 64, 0, stream>>>((const unsigned short*)d_in[0], flag);

  // ---- bf16 input path (want=1) ----
  {
    const __hip_bfloat16* x      = (const __hip_bfloat16*)d_in[0];
    const __hip_bfloat16* W_in   = (const __hip_bfloat16*)d_in[1];
    const __hip_bfloat16* conv_xw = (const __hip_bfloat16*)d_in[2];
    const __hip_bfloat16* conv_xb = (const __hip_bfloat16*)d_in[3];
    const __hip_bfloat16* conv_zw = (const __hip_bfloat16*)d_in[4];
    const __hip_bfloat16* conv_zb = (const __hip_bfloat16*)d_in[5];
    const __hip_bfloat16* W_xdbl = (const __hip_bfloat16*)d_in[6];
    const __hip_bfloat16* W_dt   = (const __hip_bfloat16*)d_in[7];
    const __hip_bfloat16* inv_dt = (const __hip_bfloat16*)d_in[8];
    const __hip_bfloat16* Dvec   = (const __hip_bfloat16*)d_in[9];
    const __hip_bfloat16* W_out  = (const __hip_bfloat16*)d_in[10];
    const __hip_bfloat16* b_out  = (const __hip_bfloat16*)d_in[11];

    mfma_gemm_kernel<__hip_bfloat16, __hip_bfloat16, float>
        <<<dim3(DI / BN, MROWS / BM), 256, 0, stream>>>(
        flag, 1, x, W_in, (const __hip_bfloat16*)nullptr, xz, MROWS, DI, DM);
    conv_silu_kernel<__hip_bfloat16><<<(MROWS * DH) / 256, 256, 0, stream>>>(
        flag, 1, xz, conv_xw, conv_xb, conv_zw, conv_zb, xs_conv, cat);
    xdbl_kernel<__hip_bfloat16><<<MROWS / 4, 128, 0, stream>>>(
        flag, 1, xs_conv, W_xdbl, xdbl);
    delta_kernel<__hip_bfloat16><<<MROWS * 4, 256, 0, stream>>>(
        flag, 1, xdbl, W_dt, inv_dt, delta);
    scan_pass1<<<dim3(4, NCH, B_SZ), 256, 0, stream>>>(
        flag, 1, delta, xs_conv, xdbl, Echunks, hp);
    scan_pass2<<<256, 256, 0, stream>>>(flag, 1, Echunks, hp, hs);
    scan_pass3<__hip_bfloat16><<<dim3(4, NCH, B_SZ), 256, 0, stream>>>(
        flag, 1, delta, xs_conv, xdbl, hs, Dvec, cat);
    mfma_gemm_kernel<__hip_bfloat16, __hip_bfloat16, __hip_bfloat16>
        <<<dim3(DM / BN, MROWS / BM), 256, 0, stream>>>(
        flag, 1, cat, W_out, b_out, (__hip_bfloat16*)d_out, MROWS, DM, DI);
  }

  // ---- fp32 input path (want=0) ----
  {
    const float* x      = (const float*)d_in[0];
    const float* W_in   = (const float*)d_in[1];
    const float* conv_xw = (const float*)d_in[2];
    const float* conv_xb = (const float*)d_in[3];
    const float* conv_zw = (const float*)d_in[4];
    const float* conv_zb = (const float*)d_in[5];
    const float* W_xdbl = (const float*)d_in[6];
    const float* W_dt   = (const float*)d_in[7];
    const float* inv_dt = (const float*)d_in[8];
    const float* Dvec   = (const float*)d_in[9];
    const float* W_out  = (const float*)d_in[10];
    const float* b_out  = (const float*)d_in[11];

    mfma_gemm_kernel<float, float, float>
        <<<dim3(DI / BN, MROWS / BM), 256, 0, stream>>>(
        flag, 0, x, W_in, (const float*)nullptr, xz, MROWS, DI, DM);
    conv_silu_kernel<float><<<(MROWS * DH) / 256, 256, 0, stream>>>(
        flag, 0, xz, conv_xw, conv_xb, conv_zw, conv_zb, xs_conv, cat);
    xdbl_kernel<float><<<MROWS / 4, 128, 0, stream>>>(
        flag, 0, xs_conv, W_xdbl, xdbl);
    delta_kernel<float><<<MROWS * 4, 256, 0, stream>>>(
        flag, 0, xdbl, W_dt, inv_dt, delta);
    scan_pass1<<<dim3(4, NCH, B_SZ), 256, 0, stream>>>(
        flag, 0, delta, xs_conv, xdbl, Echunks, hp);
    scan_pass2<<<256, 256, 0, stream>>>(flag, 0, Echunks, hp, hs);
    scan_pass3<float><<<dim3(4, NCH, B_SZ), 256, 0, stream>>>(
        flag, 0, delta, xs_conv, xdbl, hs, Dvec, cat);
    mfma_gemm_kernel<__hip_bfloat16, float, float>
        <<<dim3(DM / BN, MROWS / BM), 256, 0, stream>>>(
        flag, 0, cat, W_out, b_out, (float*)d_out, MROWS, DM, DI);
  }
}

// Round 5
// 485.980 us; speedup vs baseline: 4.1827x; 1.1573x over previous
//
#include <hip/hip_runtime.h>
#include <hip/hip_bf16.h>
#include <math.h>

#define B_SZ 4
#define LSEQ 2048
#define DM 1024
#define DI 2048
#define DH 1024
#define DS 16
#define DTR 64
#define RTOT 96
#define MROWS (B_SZ * LSEQ) /* 8192 */

// scan chunking
#define NCH 32
#define CHUNK 64 /* LSEQ / NCH */

typedef short bf8_t __attribute__((ext_vector_type(8)));
typedef float f4_t __attribute__((ext_vector_type(4)));

__device__ __forceinline__ unsigned short f2bfbits(float v) {
  __hip_bfloat16 h = __float2bfloat16(v);
  return *(unsigned short*)&h;
}

// async global->LDS 16B per lane; LDS dest is wave-uniform base + lane*16
__device__ __forceinline__ void gl_lds16(const void* g, void* l) {
  __builtin_amdgcn_global_load_lds(
      (const __attribute__((address_space(1))) unsigned int*)g,
      (__attribute__((address_space(3))) unsigned int*)l,
      16, 0, 0);
}

__device__ __forceinline__ void ld8f(const float* p, unsigned short* d) {
  const float4 a = ((const float4*)p)[0];
  const float4 b = ((const float4*)p)[1];
  d[0] = f2bfbits(a.x); d[1] = f2bfbits(a.y); d[2] = f2bfbits(a.z); d[3] = f2bfbits(a.w);
  d[4] = f2bfbits(b.x); d[5] = f2bfbits(b.y); d[6] = f2bfbits(b.z); d[7] = f2bfbits(b.w);
}

// ---------------- dtype probe (1 = bf16 inputs, 0 = fp32 inputs) ----------------
__global__ void probe_kernel(const unsigned short* __restrict__ p, int* __restrict__ flag) {
  int lane = threadIdx.x;  // 64 lanes
  int sane = 0;
#pragma unroll
  for (int j = 0; j < 4; j++) {
    unsigned short lo = p[(lane * 4 + j) * 2];
    int e = (lo >> 7) & 0xFF;
    sane += (e <= 130) ? 1 : 0;
  }
  sane += __shfl_xor(sane, 1, 64);
  sane += __shfl_xor(sane, 2, 64);
  sane += __shfl_xor(sane, 4, 64);
  sane += __shfl_xor(sane, 8, 64);
  sane += __shfl_xor(sane, 16, 64);
  sane += __shfl_xor(sane, 32, 64);
  if (lane == 0) *flag = (sane >= 220) ? 1 : 0;
}

// ---------------- prep: canonicalize small weights to fp32 ----------------
// segments: conv_xw 4096 | conv_xb 1024 | conv_zw 4096 | conv_zb 1024 |
//           W_xdbl 98304 | W_dt 65536 | inv_dt 1024 | Dvec 1024 | b_out 1024
#define PREP_TOT 177152
__global__ __launch_bounds__(256) void prep_kernel(
    const int* __restrict__ flag,
    const void* s0, const void* s1, const void* s2, const void* s3,
    const void* s4, const void* s5, const void* s6, const void* s7,
    const void* s8, float* __restrict__ out) {
  int i = blockIdx.x * 256 + threadIdx.x;
  if (i >= PREP_TOT) return;
  const void* src; int off;
  if      (i < 4096)   { src = s0; off = i; }
  else if (i < 5120)   { src = s1; off = i - 4096; }
  else if (i < 9216)   { src = s2; off = i - 5120; }
  else if (i < 10240)  { src = s3; off = i - 9216; }
  else if (i < 108544) { src = s4; off = i - 10240; }
  else if (i < 174080) { src = s5; off = i - 108544; }
  else if (i < 175104) { src = s6; off = i - 174080; }
  else if (i < 176128) { src = s7; off = i - 175104; }
  else                 { src = s8; off = i - 176128; }
  float v = (*flag == 1) ? __bfloat162float(((const __hip_bfloat16*)src)[off])
                         : ((const float*)src)[off];
  out[i] = v;
}

// ---------------- transpose: Wt[n][k] bf16 <- W[k][n] (dtype by flag) ----------------
__global__ __launch_bounds__(256) void transpose_kernel(
    const int* __restrict__ flag, const void* __restrict__ W,
    unsigned short* __restrict__ Wt, int K, int N) {
  __shared__ unsigned short tile[32][33];
  int n0 = blockIdx.x * 32, k0 = blockIdx.y * 32;
  int c = threadIdx.x & 31, r8 = threadIdx.x >> 5;
  bool isbf = (*flag == 1);
#pragma unroll
  for (int p = 0; p < 4; p++) {
    int r = r8 + p * 8;
    unsigned short v;
    if (isbf) v = ((const unsigned short*)W)[(size_t)(k0 + r) * N + n0 + c];
    else      v = f2bfbits(((const float*)W)[(size_t)(k0 + r) * N + n0 + c]);
    tile[r][c] = v;
  }
  __syncthreads();
#pragma unroll
  for (int p = 0; p < 4; p++) {
    int r = r8 + p * 8;
    Wt[(size_t)(n0 + r) * K + k0 + c] = tile[c][r];
  }
}

// ---------------- MFMA GEMM (B^T): C[M,N] = A[M,K] @ Bt[N,K]^T (+bias) ----------------
// 128x128 tile, BK=32, 4 waves 2x2, wave 64x64 = 4x4 mfma_f32_16x16x32_bf16.
// Unpadded LDS, XOR-swizzled 16B chunks: chunk' = ki ^ ((row>>1)&3)  (2-way = free).
// a_mode: 1 = A always bf16; 0 = A dtype follows flag.
// out_mode: 0 = out always bf16; 1 = out bf16 iff flag==1 else f32.
__global__ __launch_bounds__(256) void gemm_a_bt(
    const int* __restrict__ flag, int a_mode, int out_mode,
    const void* __restrict__ A, const unsigned short* __restrict__ Bt,
    const float* __restrict__ bias, void* __restrict__ C,
    int M, int N, int K) {
  __shared__ __align__(16) unsigned short As[128 * 32];
  __shared__ __align__(16) unsigned short Bs[128 * 32];
  const int fl = *flag;
  const bool a_bf = (a_mode == 1) || (fl == 1);
  const bool o_bf = (out_mode == 0) || (fl == 1);
  const int tid = threadIdx.x;
  const int lane = tid & 63;
  const int wave = tid >> 6;
  const int quad = lane >> 4;
  const int l16 = lane & 15;
  const int wm = (wave & 1) * 64;
  const int wn = (wave >> 1) * 64;
  const int m0 = blockIdx.y * 128;
  const int n0 = blockIdx.x * 128;

  f4_t acc[4][4] = {};

  for (int k0 = 0; k0 < K; k0 += 32) {
    if (a_bf) {
      const unsigned short* Ab = (const unsigned short*)A;
#pragma unroll
      for (int j = 0; j < 2; j++) {
        int ch = tid + j * 256;
        int mi = ch >> 2;
        int ki = (ch & 3) ^ ((mi >> 1) & 3);
        gl_lds16(Ab + (size_t)(m0 + mi) * K + k0 + ki * 8,
                 &As[(j * 256 + wave * 64) * 8]);
      }
    } else {
      const float* Af = (const float*)A;
#pragma unroll
      for (int j = 0; j < 2; j++) {
        int ch = tid + j * 256;
        int mi = ch >> 2;
        int ki = (ch & 3) ^ ((mi >> 1) & 3);
        unsigned short tmp[8];
        ld8f(Af + (size_t)(m0 + mi) * K + k0 + ki * 8, tmp);
        *(uint4*)&As[ch * 8] = *(uint4*)tmp;
      }
    }
#pragma unroll
    for (int j = 0; j < 2; j++) {
      int ch = tid + j * 256;
      int ni = ch >> 2;
      int ki = (ch & 3) ^ ((ni >> 1) & 3);
      gl_lds16(Bt + (size_t)(n0 + ni) * K + k0 + ki * 8,
               &Bs[(j * 256 + wave * 64) * 8]);
    }
    __syncthreads();

    bf8_t af[4], bfr[4];
#pragma unroll
    for (int ti = 0; ti < 4; ti++) {
      int r = wm + ti * 16 + l16;
      af[ti] = *(const bf8_t*)&As[(r * 4 + (quad ^ ((r >> 1) & 3))) * 8];
    }
#pragma unroll
    for (int tj = 0; tj < 4; tj++) {
      int r = wn + tj * 16 + l16;
      bfr[tj] = *(const bf8_t*)&Bs[(r * 4 + (quad ^ ((r >> 1) & 3))) * 8];
    }
#pragma unroll
    for (int ti = 0; ti < 4; ti++)
#pragma unroll
      for (int tj = 0; tj < 4; tj++)
        acc[ti][tj] = __builtin_amdgcn_mfma_f32_16x16x32_bf16(
            af[ti], bfr[tj], acc[ti][tj], 0, 0, 0);
    __syncthreads();
  }

  // epilogue: C/D layout col=lane&15, row=quad*4+reg (verified m89/m91)
#pragma unroll
  for (int ti = 0; ti < 4; ti++) {
#pragma unroll
    for (int tj = 0; tj < 4; tj++) {
      int col = n0 + wn + tj * 16 + l16;
      float bv = bias ? bias[col] : 0.f;
#pragma unroll
      for (int r = 0; r < 4; r++) {
        int row = m0 + wm + ti * 16 + quad * 4 + r;
        float v = acc[ti][tj][r] + bv;
        if (o_bf) ((__hip_bfloat16*)C)[(size_t)row * N + col] = __float2bfloat16(v);
        else      ((float*)C)[(size_t)row * N + col] = v;
      }
    }
  }
}

// ---------------- depthwise conv (k=4, SAME: pad_low=1) + SiLU, both halves ----------------
__global__ __launch_bounds__(256) void conv_silu_kernel(
    const __hip_bfloat16* __restrict__ xz,
    const float* __restrict__ wx, const float* __restrict__ bx,
    const float* __restrict__ wz, const float* __restrict__ bz,
    float* __restrict__ xs_conv, __hip_bfloat16* __restrict__ cat) {
  int gid = blockIdx.x * 256 + threadIdx.x;  // M*1024 threads
  int c = gid & 1023;
  int m = gid >> 10;
  int t = m & (LSEQ - 1);
  float ax = bx[c];
  float az = bz[c];
#pragma unroll
  for (int j = 0; j < 4; j++) {
    int tt = t - 1 + j;
    if (tt < 0 || tt >= LSEQ) continue;
    size_t row = (size_t)(m - t + tt);
    float vx = __bfloat162float(xz[row * DI + c]);
    float vz = __bfloat162float(xz[row * DI + DH + c]);
    ax += wx[j * DH + c] * vx;
    az += wz[j * DH + c] * vz;
  }
  float sx = ax / (1.f + __expf(-ax));
  float sz = az / (1.f + __expf(-az));
  xs_conv[(size_t)m * DH + c] = sx;
  cat[(size_t)m * DI + DH + c] = __float2bfloat16(sz);
}

// ---------------- x_dbl = xs_conv @ W_xdbl  (K=1024, N=96) ----------------
__global__ __launch_bounds__(128) void xdbl_kernel(
    const float* __restrict__ xs_conv, const float* __restrict__ W,
    float* __restrict__ xdbl) {
  __shared__ float xs_s[4][128];
  int r = threadIdx.x;
  int m0 = blockIdx.x * 4;
  float acc[4] = {0.f, 0.f, 0.f, 0.f};
  for (int k0 = 0; k0 < DH; k0 += 128) {
#pragma unroll
    for (int i = 0; i < 4; i++) {
      int e = threadIdx.x + i * 128;
      xs_s[e >> 7][e & 127] = xs_conv[(size_t)(m0 + (e >> 7)) * DH + k0 + (e & 127)];
    }
    __syncthreads();
    if (r < RTOT) {
      for (int kk = 0; kk < 128; kk++) {
        float w = W[(size_t)(k0 + kk) * RTOT + r];
#pragma unroll
        for (int i = 0; i < 4; i++) acc[i] += w * xs_s[i][kk];
      }
    }
    __syncthreads();
  }
  if (r < RTOT) {
#pragma unroll
    for (int i = 0; i < 4; i++) xdbl[(size_t)(m0 + i) * RTOT + r] = acc[i];
  }
}

// ---------------- delta = softplus(dt_low @ W_dt + 2*inv_dt)  (K=64, N=1024) ----------------
__global__ __launch_bounds__(256) void delta_kernel(
    const float* __restrict__ xdbl, const float* __restrict__ Wdt,
    const float* __restrict__ inv_dt, float* __restrict__ delta) {
  int m = blockIdx.x >> 2;
  int d = ((blockIdx.x & 3) << 8) + threadIdx.x;
  __shared__ float xr[DTR];
  if (threadIdx.x < DTR) xr[threadIdx.x] = xdbl[(size_t)m * RTOT + threadIdx.x];
  __syncthreads();
  float acc = 0.f;
#pragma unroll 8
  for (int rr = 0; rr < DTR; rr++) acc += xr[rr] * Wdt[(size_t)rr * DH + d];
  float v = acc + 2.f * inv_dt[d];
  float sp = (v > 0.f) ? (v + log1pf(__expf(-v))) : log1pf(__expf(v));
  delta[(size_t)m * DH + d] = sp;
}

// ---------------- chunked selective scan ----------------
__global__ __launch_bounds__(256) void scan_pass1(
    const float* __restrict__ delta, const float* __restrict__ u,
    const float* __restrict__ xdbl,
    float* __restrict__ Echunks, float* __restrict__ hp) {
  const int tid = threadIdx.x;
  const int d = blockIdx.x * 256 + tid;
  const int c = blockIdx.y, b = blockIdx.z;
  const int row0 = b * LSEQ + c * CHUNK;
  __shared__ float sBC[CHUNK][32];  // [t][0..15]=B, [16..31]=C
#pragma unroll
  for (int i = 0; i < 2; i++) {
    int task = tid + i * 256;
    int r = task >> 3, seg = task & 7;
    *(float4*)&sBC[r][seg * 4] =
        *(const float4*)&xdbl[(size_t)(row0 + r) * RTOT + DTR + seg * 4];
  }
  __syncthreads();
  float h[16];
#pragma unroll
  for (int n = 0; n < 16; n++) h[n] = 0.f;
  float E = 1.f;
  for (int t = 0; t < CHUNK; t++) {
    size_t off = (size_t)(row0 + t) * DH + d;
    float dt = delta[off], ut = u[off];
    float e = __expf(-dt);
    E *= e;
    float du = dt * ut;
    float p = 1.f;
#pragma unroll
    for (int n = 0; n < 16; n++) {
      p *= e;
      h[n] = fmaf(p, h[n], du * sBC[t][n]);
    }
  }
  Echunks[((size_t)c * B_SZ + b) * DH + d] = E;
#pragma unroll
  for (int n = 0; n < 16; n++)
    hp[(((size_t)c * B_SZ + b) * 16 + n) * DH + d] = h[n];
}

__global__ __launch_bounds__(256) void scan_pass2(
    const float* __restrict__ Echunks, const float* __restrict__ hp,
    float* __restrict__ hs) {
  int t = blockIdx.x * 256 + threadIdx.x;
  int d = t & 1023;
  int n = (t >> 10) & 15;
  int b = t >> 14;
  float h = 0.f;
  const int k0 = n + 1;
  for (int c = 0; c < NCH; c++) {
    float E = Echunks[((size_t)c * B_SZ + b) * DH + d];
    float a = 1.f, base = E;
    int k = k0;
#pragma unroll
    for (int i = 0; i < 5; i++) {
      if (k & 1) a *= base;
      base *= base;
      k >>= 1;
    }
    size_t idx = (((size_t)c * B_SZ + b) * 16 + n) * DH + d;
    hs[idx] = h;
    h = fmaf(a, h, hp[idx]);
  }
}

__global__ __launch_bounds__(256) void scan_pass3(
    const float* __restrict__ delta, const float* __restrict__ u,
    const float* __restrict__ xdbl, const float* __restrict__ hs,
    const float* __restrict__ Dvec, __hip_bfloat16* __restrict__ cat) {
  const int tid = threadIdx.x;
  const int d = blockIdx.x * 256 + tid;
  const int c = blockIdx.y, b = blockIdx.z;
  const int row0 = b * LSEQ + c * CHUNK;
  __shared__ float sBC[CHUNK][32];
#pragma unroll
  for (int i = 0; i < 2; i++) {
    int task = tid + i * 256;
    int r = task >> 3, seg = task & 7;
    *(float4*)&sBC[r][seg * 4] =
        *(const float4*)&xdbl[(size_t)(row0 + r) * RTOT + DTR + seg * 4];
  }
  __syncthreads();
  float h[16];
#pragma unroll
  for (int n = 0; n < 16; n++)
    h[n] = hs[(((size_t)c * B_SZ + b) * 16 + n) * DH + d];
  const float Dd = Dvec[d];
  for (int t = 0; t < CHUNK; t++) {
    size_t off = (size_t)(row0 + t) * DH + d;
    float dt = delta[off], ut = u[off];
    float e = __expf(-dt);
    float du = dt * ut;
    float p = 1.f, y = 0.f;
#pragma unroll
    for (int n = 0; n < 16; n++) {
      p *= e;
      h[n] = fmaf(p, h[n], du * sBC[t][n]);
      y = fmaf(h[n], sBC[t][16 + n], y);
    }
    y = fmaf(ut, Dd, y);
    cat[(size_t)(row0 + t) * DI + d] = __float2bfloat16(y);
  }
}

extern "C" void kernel_launch(void* const* d_in, const int* in_sizes, int n_in,
                              void* d_out, int out_size, void* d_ws, size_t ws_size,
                              hipStream_t stream) {
  char* ws = (char*)d_ws;
  // layout (MB offsets):
  // [0,32): xz bf16 [8192][2048]; later delta fp32 [8192][1024] (xz dead after conv)
  // [32,64): xs_conv fp32
  // [64,96): cat bf16 (y cols 0..1023, z cols 1024..2047)
  // [96,99): xdbl fp32 [8192][96]
  // [100,100.5): Echunks | [101,109): hp | [110,118): hs
  // [118,122): Wt_in bf16 [2048][1024] | [122,126): Wt_out bf16 [1024][2048]
  // [126,+708KB): canonical fp32 weights | [127]: flag
  __hip_bfloat16* xz  = (__hip_bfloat16*)(ws);
  float* delta        = (float*)(ws);
  float* xs_conv      = (float*)(ws + ((size_t)32 << 20));
  __hip_bfloat16* cat = (__hip_bfloat16*)(ws + ((size_t)64 << 20));
  float* xdbl         = (float*)(ws + ((size_t)96 << 20));
  float* Echunks      = (float*)(ws + ((size_t)100 << 20));
  float* hp           = (float*)(ws + ((size_t)101 << 20));
  float* hs           = (float*)(ws + ((size_t)110 << 20));
  unsigned short* Wt_in  = (unsigned short*)(ws + ((size_t)118 << 20));
  unsigned short* Wt_out = (unsigned short*)(ws + ((size_t)122 << 20));
  float* cw           = (float*)(ws + ((size_t)126 << 20));
  int* flag           = (int*)(ws + ((size_t)127 << 20));

  const float* conv_xwf = cw + 0;
  const float* conv_xbf = cw + 4096;
  const float* conv_zwf = cw + 5120;
  const float* conv_zbf = cw + 9216;
  const float* Wxf      = cw + 10240;
  const float* Wdtf     = cw + 108544;
  const float* inv_dtf  = cw + 174080;
  const float* Df       = cw + 175104;
  const float* b_outf   = cw + 176128;

  probe_kernel<<<1, 64, 0, stream>>>((const unsigned short*)d_in[0], flag);
  prep_kernel<<<PREP_TOT / 256, 256, 0, stream>>>(
      flag, d_in[2], d_in[3], d_in[4], d_in[5], d_in[6], d_in[7], d_in[8],
      d_in[9], d_in[11], cw);
  // Wt_in[n][k] <- W_in[k=1024][n=2048]
  transpose_kernel<<<dim3(DI / 32, DM / 32), 256, 0, stream>>>(
      flag, d_in[1], Wt_in, DM, DI);
  // Wt_out[n][k] <- W_out[k=2048][n=1024]
  transpose_kernel<<<dim3(DM / 32, DI / 32), 256, 0, stream>>>(
      flag, d_in[10], Wt_out, DI, DM);

  // 1) xz = x @ W_in  (M=8192,N=2048,K=1024), out bf16
  gemm_a_bt<<<dim3(DI / 128, MROWS / 128), 256, 0, stream>>>(
      flag, /*a_mode=*/0, /*out_mode=*/0, d_in[0], Wt_in, (const float*)nullptr,
      xz, MROWS, DI, DM);
  // 2) conv + silu
  conv_silu_kernel<<<(MROWS * DH) / 256, 256, 0, stream>>>(
      xz, conv_xwf, conv_xbf, conv_zwf, conv_zbf, xs_conv, cat);
  // 3) x_dbl
  xdbl_kernel<<<MROWS / 4, 128, 0, stream>>>(xs_conv, Wxf, xdbl);
  // 4) delta (overwrites dead xz region)
  delta_kernel<<<MROWS * 4, 256, 0, stream>>>(xdbl, Wdtf, inv_dtf, delta);
  // 5) chunked scan
  scan_pass1<<<dim3(4, NCH, B_SZ), 256, 0, stream>>>(delta, xs_conv, xdbl, Echunks, hp);
  scan_pass2<<<256, 256, 0, stream>>>(Echunks, hp, hs);
  scan_pass3<<<dim3(4, NCH, B_SZ), 256, 0, stream>>>(delta, xs_conv, xdbl, hs, Df, cat);
  // 6) out = cat @ W_out + b_out  (M=8192,N=1024,K=2048)
  gemm_a_bt<<<dim3(DM / 128, MROWS / 128), 256, 0, stream>>>(
      flag, /*a_mode=*/1, /*out_mode=*/1, cat, Wt_out, b_outf, d_out,
      MROWS, DM, DI);
}